// Round 1
// baseline (321.933 us; speedup 1.0000x reference)
//
#include <hip/hip_runtime.h>
#include <math.h>

#define NF 32

// ---- kernel 1: out-degree via atomics --------------------------------------
__global__ void deg_kernel(const int* __restrict__ src, float* __restrict__ deg, int E) {
    int e = blockIdx.x * blockDim.x + threadIdx.x;
    if (e < E) atomicAdd(&deg[src[e]], 1.0f);
}

// ---- kernel 2: deg -> dis = deg>0 ? rsqrt(max(deg,1)) : 0 (in place) -------
__global__ void dis_kernel(float* deg, int N) {
    int i = blockIdx.x * blockDim.x + threadIdx.x;
    if (i < N) {
        float d = deg[i];
        deg[i] = (d > 0.0f) ? rsqrtf(fmaxf(d, 1.0f)) : 0.0f;
    }
}

// ---- kernel 3: edge scatter: tx1[dst] += norm * x[src] ---------------------
// one thread per (edge, feature): tid>>5 = edge, tid&31 = feature
__global__ void scatter_kernel(const int* __restrict__ src, const int* __restrict__ dst,
                               const float* __restrict__ dis, const float* __restrict__ x,
                               float* __restrict__ tx1, int E) {
    long long tid = (long long)blockIdx.x * blockDim.x + threadIdx.x;
    int e = (int)(tid >> 5);
    int f = (int)(tid & 31);
    if (e >= E) return;
    int s = src[e];
    int d = dst[e];
    float nrm = -dis[s] * dis[d];
    float v = x[s * NF + f] * nrm;
    atomicAdd(&tx1[d * NF + f], v);
}

// ---- kernel 4: fused gates + readout ---------------------------------------
// block = 256 threads = 8 nodes x 32 feature-lanes
__global__ __launch_bounds__(256) void gate_kernel(
    const float* __restrict__ x, const float* __restrict__ tx1,
    const float* __restrict__ Wxz0, const float* __restrict__ Wxz1,
    const float* __restrict__ bxz,  const float* __restrict__ bhz,
    const float* __restrict__ Wxh0, const float* __restrict__ Wxh1,
    const float* __restrict__ bxh,  const float* __restrict__ bhh,
    const float* __restrict__ Wl,   const float* __restrict__ bl,
    float* __restrict__ out, int N)
{
    __shared__ float sWz0[NF * NF], sWz1[NF * NF], sWh0[NF * NF], sWh1[NF * NF];
    __shared__ float sbz[NF], sbh[NF], sWl[NF];
    __shared__ float sx[8][NF + 1], st[8][NF + 1];

    int t = threadIdx.x;
    for (int i = t; i < NF * NF; i += 256) {
        sWz0[i] = Wxz0[i];
        sWz1[i] = Wxz1[i];
        sWh0[i] = Wxh0[i];
        sWh1[i] = Wxh1[i];
    }
    if (t < NF) {
        sbz[t] = bxz[t] + bhz[t];
        sbh[t] = bxh[t] + bhh[t];
        sWl[t] = Wl[t];
    }

    int nl = t >> 5;          // node within block (0..7)
    int f  = t & 31;          // feature lane (0..31)
    int node = blockIdx.x * 8 + nl;

    if (node < N) {
        sx[nl][f] = x[node * NF + f];
        st[nl][f] = tx1[node * NF + f];
    }
    __syncthreads();
    if (node >= N) return;

    float az = sbz[f];
    float ah = sbh[f];
    #pragma unroll
    for (int k = 0; k < NF; ++k) {
        float xv = sx[nl][k];
        float tv = st[nl][k];
        az += xv * sWz0[k * NF + f] + tv * sWz1[k * NF + f];
        ah += xv * sWh0[k * NF + f] + tv * sWh1[k * NF + f];
    }

    float z  = 1.0f / (1.0f + expf(-az));
    float ht = tanhf(ah);
    float h  = (1.0f - z) * ht;
    float r  = fmaxf(h, 0.0f);
    float c  = r * sWl[f];

    // reduce over the 32 feature lanes (xor masks stay within 32-lane half)
    #pragma unroll
    for (int m = 16; m >= 1; m >>= 1) c += __shfl_xor(c, m, 64);

    if (f == 0) out[node] = c + bl[0];
}

extern "C" void kernel_launch(void* const* d_in, const int* in_sizes, int n_in,
                              void* d_out, int out_size, void* d_ws, size_t ws_size,
                              hipStream_t stream) {
    const float* x    = (const float*)d_in[0];
    const int*   edge = (const int*)d_in[1];   // [2, E] row-major: src then dst
    const float* Wxz0 = (const float*)d_in[2];
    const float* Wxz1 = (const float*)d_in[3];
    const float* bxz  = (const float*)d_in[4];
    const float* bhz  = (const float*)d_in[7];
    const float* Wxh0 = (const float*)d_in[14];
    const float* Wxh1 = (const float*)d_in[15];
    const float* bxh  = (const float*)d_in[16];
    const float* bhh  = (const float*)d_in[19];
    const float* Wl   = (const float*)d_in[20];
    const float* bl   = (const float*)d_in[21];
    float* out = (float*)d_out;

    int N = in_sizes[0] / NF;
    int E = in_sizes[1] / 2;

    // workspace layout: deg/dis [Npad] | tx1 [N*32]
    int Npad = (N + 127) & ~127;
    float* deg = (float*)d_ws;
    float* tx1 = deg + Npad;

    size_t zero_bytes = (size_t)(Npad + (size_t)N * NF) * sizeof(float);
    hipMemsetAsync(d_ws, 0, zero_bytes, stream);

    deg_kernel<<<(E + 255) / 256, 256, 0, stream>>>(edge, deg, E);
    dis_kernel<<<(N + 255) / 256, 256, 0, stream>>>(deg, N);

    long long scatter_threads = (long long)E * NF;
    int scatter_blocks = (int)((scatter_threads + 255) / 256);
    scatter_kernel<<<scatter_blocks, 256, 0, stream>>>(edge, edge + E, deg, x, tx1, E);

    gate_kernel<<<(N + 7) / 8, 256, 0, stream>>>(
        x, tx1, Wxz0, Wxz1, bxz, bhz, Wxh0, Wxh1, bxh, bhh, Wl, bl, out, N);
}